// Round 2
// baseline (569.624 us; speedup 1.0000x reference)
//
#include <hip/hip_runtime.h>
#include <hip/hip_cooperative_groups.h>
#include <stdint.h>

// Binarized 5-layer MLP, B=32768, dims 784->256->256->256->256->10.
// Single cooperative kernel: 512 blocks x 256 threads, 6 grid syncs.
// Matmuls as XOR+popcount on packed sign bits: h = in_n - 2*d.
// BN stats from exact integer sums of d per column; binarize(BN(h)) ==
// (A*d + C >= 0), A = -2*g*s, C = 2*g*s*mean_d + b  (in_n term cancels).
// Per-block state lives in LDS/registers across grid.sync() (blocks are
// resident for the whole cooperative launch): x-bits tile (8 KB LDS),
// layer-0 d tile (32 VGPRs), activation bit tiles (2x2 KB LDS).

namespace cg = cooperative_groups;
typedef unsigned long long u64;

#define RPB 64          // rows per block
#define NBLK 512        // 512 * 64 = 32768 rows

// ---- workspace layout (bytes); total ~73 KB ----
#define OFF_WB0   0u        // 256*16*8 = 32768
#define OFF_WB1   32768u    // 256*4*8  = 8192
#define OFF_WB2   40960u
#define OFF_WB3   49152u
#define OFF_WB4   57344u    // 10*4*8 = 320 (pad 512)
#define OFF_SUMD  57856u    // int32 [5][256] = 5120
#define OFF_SUMDD 62976u    // u64   [5][256] = 10240  (contiguous after SUMD)
#define STATS_INTS 3840     // (5120 + 10240) / 4

struct Params {
  const float *x, *W0, *W1, *W2, *W3, *W4;
  const float *g0, *g1, *g2, *g3, *g4;
  const float *bb0, *bb1, *bb2, *bb3, *bb4;
  u64 *wb0, *wb1, *wb2, *wb3, *wb4;
  int *sumd; u64 *sumdd;
  float *out;
};

// 784-elem row -> 13 packed u64 words (consistent permuted bit order, pads 0).
// Returns word[lane] for lane<13, 0 otherwise.
__device__ __forceinline__ u64 pack784_sel(const float* __restrict__ src,
                                           float thr, int lane) {
  u64 w[13];
  const float4* s4 = (const float4*)src;
#pragma unroll
  for (int j = 0; j < 3; ++j) {
    float4 v = s4[j * 64 + lane];
    w[4*j+0] = __ballot(v.x >= thr);
    w[4*j+1] = __ballot(v.y >= thr);
    w[4*j+2] = __ballot(v.z >= thr);
    w[4*j+3] = __ballot(v.w >= thr);
  }
  float4 v = make_float4(-1.f, -1.f, -1.f, -1.f);
  if (lane < 4) v = s4[192 + lane];
  u64 m0 = __ballot(v.x >= thr) & 0xFull;
  u64 m1 = __ballot(v.y >= thr) & 0xFull;
  u64 m2 = __ballot(v.z >= thr) & 0xFull;
  u64 m3 = __ballot(v.w >= thr) & 0xFull;
  w[12] = m0 | (m1 << 4) | (m2 << 8) | (m3 << 12);
  u64 sel = 0;
#pragma unroll
  for (int i = 0; i < 13; ++i) sel = (lane == i) ? w[i] : sel;
  return sel;
}

// 256-elem row -> 4 packed u64 words (bit l of word j <-> element 64*j+l,
// matching the in-kernel __ballot order). Returns word[lane] for lane<4.
__device__ __forceinline__ u64 pack256_sel(const float* __restrict__ src, int lane) {
  u64 w[4];
#pragma unroll
  for (int j = 0; j < 4; ++j) w[j] = __ballot(src[j * 64 + lane] >= 0.0f);
  u64 sel = 0;
#pragma unroll
  for (int i = 0; i < 4; ++i) sel = (lane == i) ? w[i] : sel;
  return sel;
}

__device__ __forceinline__ void bn_coeffs(const int* __restrict__ sumd,
                                          const u64* __restrict__ sumdd,
                                          const float* __restrict__ g,
                                          const float* __restrict__ bb, int c,
                                          float& A, float& C) {
  double md  = (double)sumd[c]  * (1.0 / 32768.0);
  double mdd = (double)sumdd[c] * (1.0 / 32768.0);
  float var = (float)(4.0 * (mdd - md * md));
  float s   = rsqrtf(var + 1e-5f);
  float gs  = g[c] * s;
  A = -2.0f * gs;
  C = fmaf(gs, (float)(2.0 * md), bb[c]);
}

// Binarize layer-k d (in dp) -> cur bit tile; then layer-(k+1) stats, with
// d_{k+1} written back into dp. Block-local except the stats atomics.
template<int NCOLS_NEXT>
__device__ __forceinline__ void layer_phase(
    int tid, int lane, int wave, uint* dp, u64* cur,
    const int* sumdK, const u64* sumddK,
    const float* gK, const float* bK,
    const u64* wbNext, int* sumdN, u64* sumddN) {
  float A, C;
  bn_coeffs(sumdK, sumddK, gK, bK, tid, A, C);
#pragma unroll
  for (int r = 0; r < RPB; ++r) {
    int d = (dp[r >> 1] >> ((r & 1) * 16)) & 0xFFFF;
    bool bit = fmaf(A, (float)d, C) >= 0.0f;
    u64 m = __ballot(bit);
    if (lane == 0) cur[r * 4 + wave] = m;
  }
  __syncthreads();
  if (tid < NCOLS_NEXT) {
    u64 wn[4];
#pragma unroll
    for (int i = 0; i < 4; ++i) wn[i] = wbNext[tid * 4 + i];
    int sd = 0, sdd = 0;
#pragma unroll
    for (int r = 0; r < RPB; ++r) {
      int d = __popcll(cur[r*4+0] ^ wn[0]) + __popcll(cur[r*4+1] ^ wn[1])
            + __popcll(cur[r*4+2] ^ wn[2]) + __popcll(cur[r*4+3] ^ wn[3]);
      sd += d; sdd += d * d;
      if (r & 1) dp[r >> 1] |= (uint)d << 16; else dp[r >> 1] = (uint)d;
    }
    atomicAdd(&sumdN[tid], sd);
    atomicAdd(&sumddN[tid], (u64)(unsigned)sdd);
  }
}

__global__ __launch_bounds__(256, 2) void fused_bmlp(Params p) {
  const int b = blockIdx.x, tid = threadIdx.x;
  const int lane = tid & 63, wave = tid >> 6;
  cg::grid_group grid = cg::this_grid();

  __shared__ u64 a0T[RPB * 16];   // 8 KB: this block's packed x rows
  __shared__ u64 abA[RPB * 4];    // 2 KB: activation bits (ping)
  __shared__ u64 abB[RPB * 4];    // 2 KB: activation bits (pong)

  // ---------- phase A: pack x rows (own tile -> LDS) + weights -> global ----------
#pragma unroll 1
  for (int it = 0; it < 16; ++it) {
    int r = it * 4 + wave;
    u64 sel = pack784_sel(p.x + (size_t)(b * RPB + r) * 784, 0.5f, lane);
    if (lane < 16) a0T[r * 16 + lane] = sel;   // words 13..15 = 0
  }
  if (b < 64) {
    int row = b * 4 + wave;
    u64 sel = pack784_sel(p.W0 + (size_t)row * 784, 0.0f, lane);
    if (lane < 16) p.wb0[row * 16 + lane] = sel;
  } else if (b < 128) {
    int row = (b - 64) * 4 + wave;
    u64 sel = pack256_sel(p.W1 + (size_t)row * 256, lane);
    if (lane < 4) p.wb1[row * 4 + lane] = sel;
  } else if (b < 192) {
    int row = (b - 128) * 4 + wave;
    u64 sel = pack256_sel(p.W2 + (size_t)row * 256, lane);
    if (lane < 4) p.wb2[row * 4 + lane] = sel;
  } else if (b < 256) {
    int row = (b - 192) * 4 + wave;
    u64 sel = pack256_sel(p.W3 + (size_t)row * 256, lane);
    if (lane < 4) p.wb3[row * 4 + lane] = sel;
  } else if (b == 256) {
    for (int row = wave; row < 10; row += 4) {
      u64 sel = pack256_sel(p.W4 + (size_t)row * 256, lane);
      if (lane < 4) p.wb4[row * 4 + lane] = sel;
    }
  }
  {
    int zi = b * 256 + tid;                    // zero all stats (15360 B)
    if (zi < STATS_INTS) ((int*)p.sumd)[zi] = 0;
  }
  grid.sync();

  // ---------- phase B: layer-0 matmul, d tile -> registers, stats0 ----------
  uint dp[32];                                 // 64 d values packed 2/u32
  {
    u64 w0r[13];
#pragma unroll
    for (int i = 0; i < 13; ++i) w0r[i] = p.wb0[tid * 16 + i];
    int sd = 0, sdd = 0;                       // d<=784 -> sdd <= 64*784^2, fits i32
#pragma unroll
    for (int r = 0; r < RPB; ++r) {
      int d = 0;
#pragma unroll
      for (int i = 0; i < 13; ++i) d += __popcll(a0T[r * 16 + i] ^ w0r[i]);
      sd += d; sdd += d * d;
      if (r & 1) dp[r >> 1] |= (uint)d << 16; else dp[r >> 1] = (uint)d;
    }
    atomicAdd(&p.sumd[tid], sd);
    atomicAdd(&p.sumdd[tid], (u64)(unsigned)sdd);
  }
  grid.sync();

  // ---------- phases C..F: binarize layer k, stats for layer k+1 ----------
  layer_phase<256>(tid, lane, wave, dp, abA, p.sumd,        p.sumdd,        p.g0, p.bb0,
                   p.wb1, p.sumd + 256,  p.sumdd + 256);
  grid.sync();
  layer_phase<256>(tid, lane, wave, dp, abB, p.sumd + 256,  p.sumdd + 256,  p.g1, p.bb1,
                   p.wb2, p.sumd + 512,  p.sumdd + 512);
  grid.sync();
  layer_phase<256>(tid, lane, wave, dp, abA, p.sumd + 512,  p.sumdd + 512,  p.g2, p.bb2,
                   p.wb3, p.sumd + 768,  p.sumdd + 768);
  grid.sync();
  layer_phase<10>(tid, lane, wave, dp, abB, p.sumd + 768,   p.sumdd + 768,  p.g3, p.bb3,
                  p.wb4, p.sumd + 1024, p.sumdd + 1024);
  grid.sync();

  // ---------- phase G: layer 4 + BN + softmax ----------
  __shared__ float sA[10], sC[10];
  __shared__ u64 w4s[40];
  if (tid < 40) w4s[tid] = p.wb4[tid];
  if (tid < 10) {
    float A, C;
    bn_coeffs(p.sumd + 1024, p.sumdd + 1024, p.g4, p.bb4, tid, A, C);
    sA[tid] = A; sC[tid] = C;
  }
  __syncthreads();
  if (tid < RPB) {
    u64 a0_ = abB[tid*4+0], a1_ = abB[tid*4+1], a2_ = abB[tid*4+2], a3_ = abB[tid*4+3];
    float y[10];
    float mx = -1e30f;
#pragma unroll
    for (int c = 0; c < 10; ++c) {
      int d = __popcll(a0_ ^ w4s[c*4+0]) + __popcll(a1_ ^ w4s[c*4+1])
            + __popcll(a2_ ^ w4s[c*4+2]) + __popcll(a3_ ^ w4s[c*4+3]);
      y[c] = fmaf(sA[c], (float)d, sC[c]);
      mx = fmaxf(mx, y[c]);
    }
    float sum = 0.0f;
#pragma unroll
    for (int c = 0; c < 10; ++c) { y[c] = __expf(y[c] - mx); sum += y[c]; }
    float inv = 1.0f / sum;
    int row = b * RPB + tid;
#pragma unroll
    for (int c = 0; c < 10; ++c) p.out[(size_t)row * 10 + c] = y[c] * inv;
  }
}

// ---------------- host ----------------
extern "C" void kernel_launch(void* const* d_in, const int* in_sizes, int n_in,
                              void* d_out, int out_size, void* d_ws, size_t ws_size,
                              hipStream_t stream) {
  (void)in_sizes; (void)n_in; (void)out_size; (void)ws_size;
  char* ws = (char*)d_ws;
  Params p;
  p.x   = (const float*)d_in[0];
  p.W0  = (const float*)d_in[1];
  p.g0  = (const float*)d_in[2];
  p.bb0 = (const float*)d_in[3];
  p.W1  = (const float*)d_in[4];
  p.g1  = (const float*)d_in[5];
  p.bb1 = (const float*)d_in[6];
  p.W2  = (const float*)d_in[7];
  p.g2  = (const float*)d_in[8];
  p.bb2 = (const float*)d_in[9];
  p.W3  = (const float*)d_in[10];
  p.g3  = (const float*)d_in[11];
  p.bb3 = (const float*)d_in[12];
  p.W4  = (const float*)d_in[13];
  p.g4  = (const float*)d_in[14];
  p.bb4 = (const float*)d_in[15];
  p.wb0 = (u64*)(ws + OFF_WB0);
  p.wb1 = (u64*)(ws + OFF_WB1);
  p.wb2 = (u64*)(ws + OFF_WB2);
  p.wb3 = (u64*)(ws + OFF_WB3);
  p.wb4 = (u64*)(ws + OFF_WB4);
  p.sumd  = (int*)(ws + OFF_SUMD);
  p.sumdd = (u64*)(ws + OFF_SUMDD);
  p.out = (float*)d_out;

  void* args[] = { &p };
  hipLaunchCooperativeKernel((void*)fused_bmlp, dim3(NBLK), dim3(256), args, 0, stream);
}

// Round 4
// 262.358 us; speedup vs baseline: 2.1712x; 2.1712x over previous
//
#include <hip/hip_runtime.h>
#include <stdint.h>

// Binarized 5-layer MLP, B=32768, dims 784->256->256->256->256->10.
// Multi-kernel pipeline (kernel boundary = grid barrier; cooperative
// grid.sync measured ~60us/sync in round 2 -- too slow).
// Matmuls as XOR+popcount on packed sign bits: h = in_n - 2*d.
// BN stats from exact integer sums of d per column, accumulated into 16
// REPLICated atomic slots (rep = blockIdx & 15) to cut same-line atomic
// serialization; consumers redundantly reduce the 16 replicas (cheap).
// binarize(BN(h)) == (A*d + C >= 0), A = -2*g*s, C = 2*g*s*mean_d + b.

typedef unsigned long long u64;

#define NREP 16

// ---- workspace layout (bytes) ----
#define OFF_WB0   0u          // 256*16*8 = 32768 (13 words used, stride 16)
#define OFF_WB1   32768u      // 256*4*8 = 8192
#define OFF_WB2   40960u
#define OFF_WB3   49152u
#define OFF_WB4   57344u      // 10*4*8 = 320 (pad 512)
#define OFF_SUMD  57856u      // int32 [16][5][256] = 81920
#define OFF_SUMDD 139776u     // u64   [16][5][256] = 163840  (contiguous after SUMD)
#define STATS_INT4 15360      // (81920+163840)/16
#define OFF_A1    (1u<<20)    // 32768*4*8 = 1 MiB each
#define OFF_A2    (2u<<20)
#define OFF_A3    (3u<<20)
#define OFF_A4    (4u<<20)
#define OFF_H0    (5u<<20)    // 32768*256*2 = 16 MiB
// total ~21 MiB

// 784-elem row -> 13 packed u64 words (consistent permuted bit order).
// Returns word[lane] for lane<13, 0 for lane 13..63.
__device__ __forceinline__ u64 pack784_sel(const float* __restrict__ src,
                                           float thr, int lane) {
  u64 w[13];
  const float4* s4 = (const float4*)src;
#pragma unroll
  for (int j = 0; j < 3; ++j) {
    float4 v = s4[j * 64 + lane];
    w[4*j+0] = __ballot(v.x >= thr);
    w[4*j+1] = __ballot(v.y >= thr);
    w[4*j+2] = __ballot(v.z >= thr);
    w[4*j+3] = __ballot(v.w >= thr);
  }
  float4 v = make_float4(-1.f, -1.f, -1.f, -1.f);
  if (lane < 4) v = s4[192 + lane];
  u64 m0 = __ballot(v.x >= thr) & 0xFull;
  u64 m1 = __ballot(v.y >= thr) & 0xFull;
  u64 m2 = __ballot(v.z >= thr) & 0xFull;
  u64 m3 = __ballot(v.w >= thr) & 0xFull;
  w[12] = m0 | (m1 << 4) | (m2 << 8) | (m3 << 12);
  u64 sel = 0;
#pragma unroll
  for (int i = 0; i < 13; ++i) sel = (lane == i) ? w[i] : sel;
  return sel;
}

// 256-elem row -> 4 packed u64 words; bit l of word j <-> element 64*j+l
// (matches the __ballot order used when building activation bits).
__device__ __forceinline__ u64 pack256_sel(const float* __restrict__ src, int lane) {
  u64 w[4];
#pragma unroll
  for (int j = 0; j < 4; ++j) w[j] = __ballot(src[j * 64 + lane] >= 0.0f);
  u64 sel = 0;
#pragma unroll
  for (int i = 0; i < 4; ++i) sel = (lane == i) ? w[i] : sel;
  return sel;
}

// Reduce the 16 stats replicas for (layer, col); return gs = g*rsqrt(var+eps)
// and mean_d.
__device__ __forceinline__ void bn_gs_md(const int* __restrict__ sumd_rep,
                                         const u64* __restrict__ sumdd_rep,
                                         int layer, int col,
                                         const float* __restrict__ g,
                                         float& gs, float& md_out) {
  long long sd = 0; u64 sdd = 0;
#pragma unroll
  for (int r = 0; r < NREP; ++r) {
    sd  += sumd_rep [(r * 5 + layer) * 256 + col];
    sdd += sumdd_rep[(r * 5 + layer) * 256 + col];
  }
  double md  = (double)sd  * (1.0 / 32768.0);
  double mdd = (double)sdd * (1.0 / 32768.0);
  float var = (float)(4.0 * (mdd - md * md));
  float s   = rsqrtf(var + 1e-5f);
  gs = g[col] * s;
  md_out = (float)md;
}

// ---------------- K1: pack all weights + zero stats ----------------
__global__ __launch_bounds__(256) void pack_weights(
    const float* __restrict__ W0, const float* __restrict__ W1,
    const float* __restrict__ W2, const float* __restrict__ W3,
    const float* __restrict__ W4,
    u64* __restrict__ wb0, u64* __restrict__ wb1, u64* __restrict__ wb2,
    u64* __restrict__ wb3, u64* __restrict__ wb4, int4* __restrict__ statsZ) {
  const int b = blockIdx.x, tid = threadIdx.x;
  const int lane = tid & 63, wave = tid >> 6;
  int gid = b * 256 + tid;
  if (gid < STATS_INT4) statsZ[gid] = make_int4(0, 0, 0, 0);
  if (b < 64) {
    int row = b * 4 + wave;
    u64 sel = pack784_sel(W0 + (size_t)row * 784, 0.0f, lane);
    if (lane < 16) wb0[row * 16 + lane] = sel;
  } else if (b < 128) {
    int row = (b - 64) * 4 + wave;
    u64 sel = pack256_sel(W1 + (size_t)row * 256, lane);
    if (lane < 4) wb1[row * 4 + lane] = sel;
  } else if (b < 192) {
    int row = (b - 128) * 4 + wave;
    u64 sel = pack256_sel(W2 + (size_t)row * 256, lane);
    if (lane < 4) wb2[row * 4 + lane] = sel;
  } else if (b < 256) {
    int row = (b - 192) * 4 + wave;
    u64 sel = pack256_sel(W3 + (size_t)row * 256, lane);
    if (lane < 4) wb3[row * 4 + lane] = sel;
  } else {
    for (int row = wave; row < 10; row += 4) {
      u64 sel = pack256_sel(W4 + (size_t)row * 256, lane);
      if (lane < 4) wb4[row * 4 + lane] = sel;
    }
  }
}

// ---------------- K2: pack x tile -> LDS, layer-0 matmul, h0 + stats0 ----------------
__global__ __launch_bounds__(256, 4) void mm0_kernel(
    const float* __restrict__ x, const u64* __restrict__ wb0,
    short* __restrict__ h0, int* __restrict__ sumd_rep, u64* __restrict__ sumdd_rep) {
  const int b = blockIdx.x, tid = threadIdx.x;
  const int lane = tid & 63, wave = tid >> 6;
  const int row0 = b * 16;
  __shared__ u64 a0T[16 * 16];
#pragma unroll
  for (int it = 0; it < 4; ++it) {
    int r = it * 4 + wave;
    u64 sel = pack784_sel(x + (size_t)(row0 + r) * 784, 0.5f, lane);
    if (lane < 16) a0T[r * 16 + lane] = sel;
  }
  __syncthreads();
  u64 w0r[13];
#pragma unroll
  for (int i = 0; i < 13; ++i) w0r[i] = wb0[tid * 16 + i];
  int sd = 0; unsigned sdd = 0;     // 16 * 784^2 = 9.8M, fits u32
#pragma unroll
  for (int r = 0; r < 16; ++r) {
    int d = 0;
#pragma unroll
    for (int i = 0; i < 13; ++i) d += __popcll(a0T[r * 16 + i] ^ w0r[i]);
    h0[(size_t)(row0 + r) * 256 + tid] = (short)(784 - 2 * d);
    sd += d; sdd += (unsigned)(d * d);
  }
  const int rep = b & (NREP - 1);
  atomicAdd(&sumd_rep [(rep * 5 + 0) * 256 + tid], sd);
  atomicAdd(&sumdd_rep[(rep * 5 + 0) * 256 + tid], (u64)sdd);
}

// ---------------- K3: binarize BN(h0) -> a1 bits, + layer-1 stats ----------------
__global__ __launch_bounds__(256, 4) void b0_kernel(
    const short* __restrict__ h0,
    int* __restrict__ sumd_rep, u64* __restrict__ sumdd_rep,
    const float* __restrict__ g0, const float* __restrict__ bb0,
    u64* __restrict__ a1, const u64* __restrict__ wb1) {
  const int b = blockIdx.x, tid = threadIdx.x;
  const int lane = tid & 63, wave = tid >> 6;
  const int row0 = b * 32;
  float gs, md;
  bn_gs_md(sumd_rep, sumdd_rep, 0, tid, g0, gs, md);
  const float mh = 784.0f - 2.0f * md;
  const float bb = bb0[tid];
  __shared__ u64 bits[32 * 4];
#pragma unroll
  for (int r = 0; r < 32; ++r) {
    float hv = (float)h0[(size_t)(row0 + r) * 256 + tid];
    bool bit = fmaf(gs, hv - mh, bb) >= 0.0f;
    u64 m = __ballot(bit);
    if (lane == 0) bits[r * 4 + wave] = m;
  }
  __syncthreads();
  if (tid < 128) a1[(size_t)row0 * 4 + tid] = bits[tid];
  u64 wn[4];
#pragma unroll
  for (int i = 0; i < 4; ++i) wn[i] = wb1[tid * 4 + i];
  int sd = 0; unsigned sdd = 0;     // 32 * 256^2 = 2.1M, fits u32
#pragma unroll
  for (int r = 0; r < 32; ++r) {
    int d = __popcll(bits[r*4+0] ^ wn[0]) + __popcll(bits[r*4+1] ^ wn[1])
          + __popcll(bits[r*4+2] ^ wn[2]) + __popcll(bits[r*4+3] ^ wn[3]);
    sd += d; sdd += (unsigned)(d * d);
  }
  const int rep = b & (NREP - 1);
  atomicAdd(&sumd_rep [(rep * 5 + 1) * 256 + tid], sd);
  atomicAdd(&sumdd_rep[(rep * 5 + 1) * 256 + tid], (u64)sdd);
}

// ---------------- K4..K6: layer k -> a_{k+1} bits + layer-(k+1) stats ----------------
template<int LAYER, int NNEXT>
__global__ __launch_bounds__(256, 4) void bmid_kernel(
    const u64* __restrict__ aK, const u64* __restrict__ wbK,
    int* __restrict__ sumd_rep, u64* __restrict__ sumdd_rep,
    const float* __restrict__ gK, const float* __restrict__ bK,
    u64* __restrict__ aN, const u64* __restrict__ wbN) {
  const int b = blockIdx.x, tid = threadIdx.x;
  const int lane = tid & 63, wave = tid >> 6;
  const int row0 = b * 32;
  __shared__ u64 ain[32 * 4];
  __shared__ u64 bits[32 * 4];
  if (tid < 128) ain[tid] = aK[(size_t)row0 * 4 + tid];
  float gs, md;
  bn_gs_md(sumd_rep, sumdd_rep, LAYER, tid, gK, gs, md);
  const float A = -2.0f * gs;
  const float C = fmaf(gs, 2.0f * md, bK[tid]);
  u64 wk[4];
#pragma unroll
  for (int i = 0; i < 4; ++i) wk[i] = wbK[tid * 4 + i];
  __syncthreads();
#pragma unroll
  for (int r = 0; r < 32; ++r) {
    int d = __popcll(ain[r*4+0] ^ wk[0]) + __popcll(ain[r*4+1] ^ wk[1])
          + __popcll(ain[r*4+2] ^ wk[2]) + __popcll(ain[r*4+3] ^ wk[3]);
    bool bit = fmaf(A, (float)d, C) >= 0.0f;
    u64 m = __ballot(bit);
    if (lane == 0) bits[r * 4 + wave] = m;
  }
  __syncthreads();
  if (tid < 128) aN[(size_t)row0 * 4 + tid] = bits[tid];
  if (tid < NNEXT) {
    u64 wn[4];
#pragma unroll
    for (int i = 0; i < 4; ++i) wn[i] = wbN[tid * 4 + i];
    int sd = 0; unsigned sdd = 0;
#pragma unroll
    for (int r = 0; r < 32; ++r) {
      int d = __popcll(bits[r*4+0] ^ wn[0]) + __popcll(bits[r*4+1] ^ wn[1])
            + __popcll(bits[r*4+2] ^ wn[2]) + __popcll(bits[r*4+3] ^ wn[3]);
      sd += d; sdd += (unsigned)(d * d);
    }
    const int rep = b & (NREP - 1);
    atomicAdd(&sumd_rep [(rep * 5 + LAYER + 1) * 256 + tid], sd);
    atomicAdd(&sumdd_rep[(rep * 5 + LAYER + 1) * 256 + tid], (u64)sdd);
  }
}

// ---------------- K7: layer 4 + BN + softmax ----------------
__global__ __launch_bounds__(256) void b4_kernel(
    const u64* __restrict__ a4, const u64* __restrict__ wb4,
    const int* __restrict__ sumd_rep, const u64* __restrict__ sumdd_rep,
    const float* __restrict__ g4, const float* __restrict__ bb4,
    float* __restrict__ out) {
  __shared__ float sA[10], sC[10];
  __shared__ u64 w4s[40];
  const int tid = threadIdx.x;
  if (tid < 40) w4s[tid] = wb4[tid];
  if (tid < 10) {
    float gs, md;
    bn_gs_md(sumd_rep, sumdd_rep, 4, tid, g4, gs, md);
    sA[tid] = -2.0f * gs;
    sC[tid] = fmaf(gs, 2.0f * md, bb4[tid]);
  }
  __syncthreads();
  const int row = blockIdx.x * 256 + tid;
  u64 a[4];
#pragma unroll
  for (int i = 0; i < 4; ++i) a[i] = a4[(size_t)row * 4 + i];
  float y[10];
  float mx = -1e30f;
#pragma unroll
  for (int c = 0; c < 10; ++c) {
    int d = __popcll(a[0] ^ w4s[c*4+0]) + __popcll(a[1] ^ w4s[c*4+1])
          + __popcll(a[2] ^ w4s[c*4+2]) + __popcll(a[3] ^ w4s[c*4+3]);
    y[c] = fmaf(sA[c], (float)d, sC[c]);
    mx = fmaxf(mx, y[c]);
  }
  float sum = 0.0f;
#pragma unroll
  for (int c = 0; c < 10; ++c) { y[c] = __expf(y[c] - mx); sum += y[c]; }
  float inv = 1.0f / sum;
#pragma unroll
  for (int c = 0; c < 10; ++c) out[(size_t)row * 10 + c] = y[c] * inv;
}

// ---------------- host ----------------
extern "C" void kernel_launch(void* const* d_in, const int* in_sizes, int n_in,
                              void* d_out, int out_size, void* d_ws, size_t ws_size,
                              hipStream_t stream) {
  (void)in_sizes; (void)n_in; (void)out_size; (void)ws_size;
  const float* x   = (const float*)d_in[0];
  const float* W0  = (const float*)d_in[1];
  const float* g0  = (const float*)d_in[2];
  const float* bb0 = (const float*)d_in[3];
  const float* W1  = (const float*)d_in[4];
  const float* g1  = (const float*)d_in[5];
  const float* bb1 = (const float*)d_in[6];
  const float* W2  = (const float*)d_in[7];
  const float* g2  = (const float*)d_in[8];
  const float* bb2 = (const float*)d_in[9];
  const float* W3  = (const float*)d_in[10];
  const float* g3  = (const float*)d_in[11];
  const float* bb3 = (const float*)d_in[12];
  const float* W4  = (const float*)d_in[13];
  const float* g4  = (const float*)d_in[14];
  const float* bb4 = (const float*)d_in[15];

  char* ws = (char*)d_ws;
  u64*   wb0 = (u64*)(ws + OFF_WB0);
  u64*   wb1 = (u64*)(ws + OFF_WB1);
  u64*   wb2 = (u64*)(ws + OFF_WB2);
  u64*   wb3 = (u64*)(ws + OFF_WB3);
  u64*   wb4 = (u64*)(ws + OFF_WB4);
  int*   sumd  = (int*)(ws + OFF_SUMD);
  u64*   sumdd = (u64*)(ws + OFF_SUMDD);
  u64*   a1 = (u64*)(ws + OFF_A1);
  u64*   a2 = (u64*)(ws + OFF_A2);
  u64*   a3 = (u64*)(ws + OFF_A3);
  u64*   a4 = (u64*)(ws + OFF_A4);
  short* h0 = (short*)(ws + OFF_H0);

  pack_weights<<<257, 256, 0, stream>>>(W0, W1, W2, W3, W4,
                                        wb0, wb1, wb2, wb3, wb4,
                                        (int4*)(ws + OFF_SUMD));
  mm0_kernel<<<2048, 256, 0, stream>>>(x, wb0, h0, sumd, sumdd);
  b0_kernel<<<1024, 256, 0, stream>>>(h0, sumd, sumdd, g0, bb0, a1, wb1);
  bmid_kernel<1, 256><<<1024, 256, 0, stream>>>(a1, wb1, sumd, sumdd, g1, bb1, a2, wb2);
  bmid_kernel<2, 256><<<1024, 256, 0, stream>>>(a2, wb2, sumd, sumdd, g2, bb2, a3, wb3);
  bmid_kernel<3, 10><<<1024, 256, 0, stream>>>(a3, wb3, sumd, sumdd, g3, bb3, a4, wb4);
  b4_kernel<<<128, 256, 0, stream>>>(a4, wb4, sumd, sumdd, g4, bb4, (float*)d_out);
}

// Round 5
// 261.063 us; speedup vs baseline: 2.1819x; 1.0050x over previous
//
#include <hip/hip_runtime.h>
#include <stdint.h>

// Binarized 5-layer MLP, B=32768, dims 784->256->256->256->256->10.
// Multi-kernel pipeline. Matmuls as XOR+popcount on packed sign bits:
// h = in_n - 2*d.  BN stats from exact integer sums of d per column into
// 16 replicated atomic slots; consumers reduce the replicas.
// binarize(BN(h)) == (A*d + C >= 0), A = -2*g*s, C = 2*g*s*mean_d + b.
// Round 5: weight bit arrays stored TRANSPOSED (wbT[word][col]) so the
// per-thread weight loads (wbT[i*256+tid]) are fully coalesced; round-4
// layout (wb[col][word], stride 128B) made every load instr touch 64
// cache lines -> mm0 was latency-bound at 59us, VALUBusy 28%.

typedef unsigned long long u64;

#define NREP 16

// ---- workspace layout (bytes) ----
#define OFF_WB0   0u          // u64 [16][256] = 32768 (words 0..12 used)
#define OFF_WB1   32768u      // u64 [4][256] = 8192
#define OFF_WB2   40960u
#define OFF_WB3   49152u
#define OFF_WB4   57344u      // u64 [4][16] = 512 (10 cols used)
#define OFF_SUMD  57856u      // int32 [16][5][256] = 81920
#define OFF_SUMDD 139776u     // u64   [16][5][256] = 163840
#define STATS_INT4 15360      // (81920+163840)/16
#define OFF_A1    (1u<<20)    // 32768*4*8 = 1 MiB each
#define OFF_A2    (2u<<20)
#define OFF_A3    (3u<<20)
#define OFF_A4    (4u<<20)
#define OFF_H0    (5u<<20)    // 32768*256*2 = 16 MiB

// 784-elem row -> 13 packed u64 words (consistent permuted bit order).
// Returns word[lane] for lane<13, 0 for lane 13..63.
__device__ __forceinline__ u64 pack784_sel(const float* __restrict__ src,
                                           float thr, int lane) {
  u64 w[13];
  const float4* s4 = (const float4*)src;
#pragma unroll
  for (int j = 0; j < 3; ++j) {
    float4 v = s4[j * 64 + lane];
    w[4*j+0] = __ballot(v.x >= thr);
    w[4*j+1] = __ballot(v.y >= thr);
    w[4*j+2] = __ballot(v.z >= thr);
    w[4*j+3] = __ballot(v.w >= thr);
  }
  float4 v = make_float4(-1.f, -1.f, -1.f, -1.f);
  if (lane < 4) v = s4[192 + lane];
  u64 m0 = __ballot(v.x >= thr) & 0xFull;
  u64 m1 = __ballot(v.y >= thr) & 0xFull;
  u64 m2 = __ballot(v.z >= thr) & 0xFull;
  u64 m3 = __ballot(v.w >= thr) & 0xFull;
  w[12] = m0 | (m1 << 4) | (m2 << 8) | (m3 << 12);
  u64 sel = 0;
#pragma unroll
  for (int i = 0; i < 13; ++i) sel = (lane == i) ? w[i] : sel;
  return sel;
}

// 256-elem row -> 4 packed u64 words; bit l of word j <-> element 64*j+l.
__device__ __forceinline__ u64 pack256_sel(const float* __restrict__ src, int lane) {
  u64 w[4];
#pragma unroll
  for (int j = 0; j < 4; ++j) w[j] = __ballot(src[j * 64 + lane] >= 0.0f);
  u64 sel = 0;
#pragma unroll
  for (int i = 0; i < 4; ++i) sel = (lane == i) ? w[i] : sel;
  return sel;
}

// Reduce the 16 stats replicas for (layer, col); gs = g*rsqrt(var+eps), mean_d.
__device__ __forceinline__ void bn_gs_md(const int* __restrict__ sumd_rep,
                                         const u64* __restrict__ sumdd_rep,
                                         int layer, int col,
                                         const float* __restrict__ g,
                                         float& gs, float& md_out) {
  long long sd = 0; u64 sdd = 0;
#pragma unroll
  for (int r = 0; r < NREP; ++r) {
    sd  += sumd_rep [(r * 5 + layer) * 256 + col];
    sdd += sumdd_rep[(r * 5 + layer) * 256 + col];
  }
  double md  = (double)sd  * (1.0 / 32768.0);
  double mdd = (double)sdd * (1.0 / 32768.0);
  float var = (float)(4.0 * (mdd - md * md));
  float s   = rsqrtf(var + 1e-5f);
  gs = g[col] * s;
  md_out = (float)md;
}

// ---------------- K1: pack all weights (transposed) + zero stats ----------------
__global__ __launch_bounds__(256) void pack_weights(
    const float* __restrict__ W0, const float* __restrict__ W1,
    const float* __restrict__ W2, const float* __restrict__ W3,
    const float* __restrict__ W4,
    u64* __restrict__ wb0, u64* __restrict__ wb1, u64* __restrict__ wb2,
    u64* __restrict__ wb3, u64* __restrict__ wb4, int4* __restrict__ statsZ) {
  const int b = blockIdx.x, tid = threadIdx.x;
  const int lane = tid & 63, wave = tid >> 6;
  int gid = b * 256 + tid;
  if (gid < STATS_INT4) statsZ[gid] = make_int4(0, 0, 0, 0);
  if (b < 64) {
    int row = b * 4 + wave;
    u64 sel = pack784_sel(W0 + (size_t)row * 784, 0.0f, lane);
    if (lane < 13) wb0[lane * 256 + row] = sel;
  } else if (b < 128) {
    int row = (b - 64) * 4 + wave;
    u64 sel = pack256_sel(W1 + (size_t)row * 256, lane);
    if (lane < 4) wb1[lane * 256 + row] = sel;
  } else if (b < 192) {
    int row = (b - 128) * 4 + wave;
    u64 sel = pack256_sel(W2 + (size_t)row * 256, lane);
    if (lane < 4) wb2[lane * 256 + row] = sel;
  } else if (b < 256) {
    int row = (b - 192) * 4 + wave;
    u64 sel = pack256_sel(W3 + (size_t)row * 256, lane);
    if (lane < 4) wb3[lane * 256 + row] = sel;
  } else {
    for (int row = wave; row < 10; row += 4) {
      u64 sel = pack256_sel(W4 + (size_t)row * 256, lane);
      if (lane < 4) wb4[lane * 16 + row] = sel;
    }
  }
}

// ---------------- K2: pack x tile -> LDS, layer-0 matmul, h0 + stats0 ----------------
__global__ __launch_bounds__(256, 4) void mm0_kernel(
    const float* __restrict__ x, const u64* __restrict__ wb0T,
    short* __restrict__ h0, int* __restrict__ sumd_rep, u64* __restrict__ sumdd_rep) {
  const int b = blockIdx.x, tid = threadIdx.x;
  const int lane = tid & 63, wave = tid >> 6;
  const int row0 = b * 16;
  __shared__ u64 a0T[16 * 16];
#pragma unroll
  for (int it = 0; it < 4; ++it) {
    int r = it * 4 + wave;
    u64 sel = pack784_sel(x + (size_t)(row0 + r) * 784, 0.5f, lane);
    if (lane < 16) a0T[r * 16 + lane] = sel;
  }
  __syncthreads();
  u64 w0r[13];
#pragma unroll
  for (int i = 0; i < 13; ++i) w0r[i] = wb0T[i * 256 + tid];   // coalesced
  int sd = 0; unsigned sdd = 0;     // 16 * 784^2 = 9.8M, fits u32
#pragma unroll
  for (int r = 0; r < 16; ++r) {
    int d = 0;
#pragma unroll
    for (int i = 0; i < 13; ++i) d += __popcll(a0T[r * 16 + i] ^ w0r[i]);
    h0[(size_t)(row0 + r) * 256 + tid] = (short)(784 - 2 * d);
    sd += d; sdd += (unsigned)(d * d);
  }
  const int rep = b & (NREP - 1);
  atomicAdd(&sumd_rep [(rep * 5 + 0) * 256 + tid], sd);
  atomicAdd(&sumdd_rep[(rep * 5 + 0) * 256 + tid], (u64)sdd);
}

// ---------------- K3: binarize BN(h0) -> a1 bits, + layer-1 stats ----------------
__global__ __launch_bounds__(256, 4) void b0_kernel(
    const short* __restrict__ h0,
    int* __restrict__ sumd_rep, u64* __restrict__ sumdd_rep,
    const float* __restrict__ g0, const float* __restrict__ bb0,
    u64* __restrict__ a1, const u64* __restrict__ wb1T) {
  const int b = blockIdx.x, tid = threadIdx.x;
  const int lane = tid & 63, wave = tid >> 6;
  const int row0 = b * 32;
  float gs, md;
  bn_gs_md(sumd_rep, sumdd_rep, 0, tid, g0, gs, md);
  const float mh = 784.0f - 2.0f * md;
  const float bb = bb0[tid];
  __shared__ u64 bits[32 * 4];
#pragma unroll
  for (int r = 0; r < 32; ++r) {
    float hv = (float)h0[(size_t)(row0 + r) * 256 + tid];
    bool bit = fmaf(gs, hv - mh, bb) >= 0.0f;
    u64 m = __ballot(bit);
    if (lane == 0) bits[r * 4 + wave] = m;
  }
  __syncthreads();
  if (tid < 128) a1[(size_t)row0 * 4 + tid] = bits[tid];
  u64 wn[4];
#pragma unroll
  for (int i = 0; i < 4; ++i) wn[i] = wb1T[i * 256 + tid];   // coalesced
  int sd = 0; unsigned sdd = 0;     // 32 * 256^2 = 2.1M, fits u32
#pragma unroll
  for (int r = 0; r < 32; ++r) {
    int d = __popcll(bits[r*4+0] ^ wn[0]) + __popcll(bits[r*4+1] ^ wn[1])
          + __popcll(bits[r*4+2] ^ wn[2]) + __popcll(bits[r*4+3] ^ wn[3]);
    sd += d; sdd += (unsigned)(d * d);
  }
  const int rep = b & (NREP - 1);
  atomicAdd(&sumd_rep [(rep * 5 + 1) * 256 + tid], sd);
  atomicAdd(&sumdd_rep[(rep * 5 + 1) * 256 + tid], (u64)sdd);
}

// ---------------- K4..K6: layer k -> a_{k+1} bits + layer-(k+1) stats ----------------
// NSTRIDE: column stride of the transposed next-weight array (256 or 16).
template<int LAYER, int NNEXT, int NSTRIDE>
__global__ __launch_bounds__(256, 4) void bmid_kernel(
    const u64* __restrict__ aK, const u64* __restrict__ wbKT,
    int* __restrict__ sumd_rep, u64* __restrict__ sumdd_rep,
    const float* __restrict__ gK, const float* __restrict__ bK,
    u64* __restrict__ aN, const u64* __restrict__ wbNT) {
  const int b = blockIdx.x, tid = threadIdx.x;
  const int lane = tid & 63, wave = tid >> 6;
  const int row0 = b * 32;
  __shared__ u64 ain[32 * 4];
  __shared__ u64 bits[32 * 4];
  if (tid < 128) ain[tid] = aK[(size_t)row0 * 4 + tid];
  float gs, md;
  bn_gs_md(sumd_rep, sumdd_rep, LAYER, tid, gK, gs, md);
  const float A = -2.0f * gs;
  const float C = fmaf(gs, 2.0f * md, bK[tid]);
  u64 wk[4];
#pragma unroll
  for (int i = 0; i < 4; ++i) wk[i] = wbKT[i * 256 + tid];   // coalesced
  __syncthreads();
#pragma unroll
  for (int r = 0; r < 32; ++r) {
    int d = __popcll(ain[r*4+0] ^ wk[0]) + __popcll(ain[r*4+1] ^ wk[1])
          + __popcll(ain[r*4+2] ^ wk[2]) + __popcll(ain[r*4+3] ^ wk[3]);
    bool bit = fmaf(A, (float)d, C) >= 0.0f;
    u64 m = __ballot(bit);
    if (lane == 0) bits[r * 4 + wave] = m;
  }
  __syncthreads();
  if (tid < 128) aN[(size_t)row0 * 4 + tid] = bits[tid];
  if (tid < NNEXT) {
    u64 wn[4];
#pragma unroll
    for (int i = 0; i < 4; ++i) wn[i] = wbNT[i * NSTRIDE + tid];
    int sd = 0; unsigned sdd = 0;
#pragma unroll
    for (int r = 0; r < 32; ++r) {
      int d = __popcll(bits[r*4+0] ^ wn[0]) + __popcll(bits[r*4+1] ^ wn[1])
            + __popcll(bits[r*4+2] ^ wn[2]) + __popcll(bits[r*4+3] ^ wn[3]);
      sd += d; sdd += (unsigned)(d * d);
    }
    const int rep = b & (NREP - 1);
    atomicAdd(&sumd_rep [(rep * 5 + LAYER + 1) * 256 + tid], sd);
    atomicAdd(&sumdd_rep[(rep * 5 + LAYER + 1) * 256 + tid], (u64)sdd);
  }
}

// ---------------- K7: layer 4 + BN + softmax ----------------
__global__ __launch_bounds__(256) void b4_kernel(
    const u64* __restrict__ a4, const u64* __restrict__ wb4T,
    const int* __restrict__ sumd_rep, const u64* __restrict__ sumdd_rep,
    const float* __restrict__ g4, const float* __restrict__ bb4,
    float* __restrict__ out) {
  __shared__ float sA[10], sC[10];
  __shared__ u64 w4s[40];
  const int tid = threadIdx.x;
  if (tid < 40) w4s[tid] = wb4T[(tid & 3) * 16 + (tid >> 2)];   // w4s[c*4+i] = word i of class c
  if (tid < 10) {
    float gs, md;
    bn_gs_md(sumd_rep, sumdd_rep, 4, tid, g4, gs, md);
    sA[tid] = -2.0f * gs;
    sC[tid] = fmaf(gs, 2.0f * md, bb4[tid]);
  }
  __syncthreads();
  const int row = blockIdx.x * 256 + tid;
  u64 a[4];
#pragma unroll
  for (int i = 0; i < 4; ++i) a[i] = a4[(size_t)row * 4 + i];
  float y[10];
  float mx = -1e30f;
#pragma unroll
  for (int c = 0; c < 10; ++c) {
    int d = __popcll(a[0] ^ w4s[c*4+0]) + __popcll(a[1] ^ w4s[c*4+1])
          + __popcll(a[2] ^ w4s[c*4+2]) + __popcll(a[3] ^ w4s[c*4+3]);
    y[c] = fmaf(sA[c], (float)d, sC[c]);
    mx = fmaxf(mx, y[c]);
  }
  float sum = 0.0f;
#pragma unroll
  for (int c = 0; c < 10; ++c) { y[c] = __expf(y[c] - mx); sum += y[c]; }
  float inv = 1.0f / sum;
#pragma unroll
  for (int c = 0; c < 10; ++c) out[(size_t)row * 10 + c] = y[c] * inv;
}

// ---------------- host ----------------
extern "C" void kernel_launch(void* const* d_in, const int* in_sizes, int n_in,
                              void* d_out, int out_size, void* d_ws, size_t ws_size,
                              hipStream_t stream) {
  (void)in_sizes; (void)n_in; (void)out_size; (void)ws_size;
  const float* x   = (const float*)d_in[0];
  const float* W0  = (const float*)d_in[1];
  const float* g0  = (const float*)d_in[2];
  const float* bb0 = (const float*)d_in[3];
  const float* W1  = (const float*)d_in[4];
  const float* g1  = (const float*)d_in[5];
  const float* bb1 = (const float*)d_in[6];
  const float* W2  = (const float*)d_in[7];
  const float* g2  = (const float*)d_in[8];
  const float* bb2 = (const float*)d_in[9];
  const float* W3  = (const float*)d_in[10];
  const float* g3  = (const float*)d_in[11];
  const float* bb3 = (const float*)d_in[12];
  const float* W4  = (const float*)d_in[13];
  const float* g4  = (const float*)d_in[14];
  const float* bb4 = (const float*)d_in[15];

  char* ws = (char*)d_ws;
  u64*   wb0 = (u64*)(ws + OFF_WB0);
  u64*   wb1 = (u64*)(ws + OFF_WB1);
  u64*   wb2 = (u64*)(ws + OFF_WB2);
  u64*   wb3 = (u64*)(ws + OFF_WB3);
  u64*   wb4 = (u64*)(ws + OFF_WB4);
  int*   sumd  = (int*)(ws + OFF_SUMD);
  u64*   sumdd = (u64*)(ws + OFF_SUMDD);
  u64*   a1 = (u64*)(ws + OFF_A1);
  u64*   a2 = (u64*)(ws + OFF_A2);
  u64*   a3 = (u64*)(ws + OFF_A3);
  u64*   a4 = (u64*)(ws + OFF_A4);
  short* h0 = (short*)(ws + OFF_H0);

  pack_weights<<<257, 256, 0, stream>>>(W0, W1, W2, W3, W4,
                                        wb0, wb1, wb2, wb3, wb4,
                                        (int4*)(ws + OFF_SUMD));
  mm0_kernel<<<2048, 256, 0, stream>>>(x, wb0, h0, sumd, sumdd);
  b0_kernel<<<1024, 256, 0, stream>>>(h0, sumd, sumdd, g0, bb0, a1, wb1);
  bmid_kernel<1, 256, 256><<<1024, 256, 0, stream>>>(a1, wb1, sumd, sumdd, g1, bb1, a2, wb2);
  bmid_kernel<2, 256, 256><<<1024, 256, 0, stream>>>(a2, wb2, sumd, sumdd, g2, bb2, a3, wb3);
  bmid_kernel<3, 10, 16><<<1024, 256, 0, stream>>>(a3, wb3, sumd, sumdd, g3, bb3, a4, wb4);
  b4_kernel<<<128, 256, 0, stream>>>(a4, wb4, sumd, sumdd, g4, bb4, (float*)d_out);
}

// Round 6
// 257.185 us; speedup vs baseline: 2.2148x; 1.0151x over previous
//
#include <hip/hip_runtime.h>
#include <stdint.h>

// Binarized 5-layer MLP, B=32768, dims 784->256->256->256->256->10.
// Multi-kernel pipeline. Matmuls as XOR+popcount on packed sign bits:
// h = in_n - 2*d.  BN stats from exact integer sums of d per column into
// 16 replicated atomic slots; consumers reduce the replicas.
// binarize(BN(h)) == (A*d + C >= 0), A = -2*g*s, C = 2*g*s*mean_d + b.
// Round 6: mm0 was latency-bound (VALUBusy 28%, HBM 16%, LDS ~16us, occ 53%)
// -> raise min-waves to 8/EU (32 waves/CU, whole 2048-block grid resident),
// hoist weight loads ahead of the x-pack phase, b128 LDS reads in inner loop.

typedef unsigned long long u64;

#define NREP 16

// ---- workspace layout (bytes) ----
#define OFF_WB0   0u          // u64 [16][256] = 32768 (words 0..12 used)
#define OFF_WB1   32768u      // u64 [4][256] = 8192
#define OFF_WB2   40960u
#define OFF_WB3   49152u
#define OFF_WB4   57344u      // u64 [4][16] = 512 (10 cols used)
#define OFF_SUMD  57856u      // int32 [16][5][256] = 81920
#define OFF_SUMDD 139776u     // u64   [16][5][256] = 163840
#define STATS_INT4 15360      // (81920+163840)/16
#define OFF_A1    (1u<<20)    // 32768*4*8 = 1 MiB each
#define OFF_A2    (2u<<20)
#define OFF_A3    (3u<<20)
#define OFF_A4    (4u<<20)
#define OFF_H0    (5u<<20)    // 32768*256*2 = 16 MiB

// 784-elem row -> 13 packed u64 words (consistent permuted bit order).
// Returns word[lane] for lane<13, 0 for lane 13..63.
__device__ __forceinline__ u64 pack784_sel(const float* __restrict__ src,
                                           float thr, int lane) {
  u64 w[13];
  const float4* s4 = (const float4*)src;
#pragma unroll
  for (int j = 0; j < 3; ++j) {
    float4 v = s4[j * 64 + lane];
    w[4*j+0] = __ballot(v.x >= thr);
    w[4*j+1] = __ballot(v.y >= thr);
    w[4*j+2] = __ballot(v.z >= thr);
    w[4*j+3] = __ballot(v.w >= thr);
  }
  float4 v = make_float4(-1.f, -1.f, -1.f, -1.f);
  if (lane < 4) v = s4[192 + lane];
  u64 m0 = __ballot(v.x >= thr) & 0xFull;
  u64 m1 = __ballot(v.y >= thr) & 0xFull;
  u64 m2 = __ballot(v.z >= thr) & 0xFull;
  u64 m3 = __ballot(v.w >= thr) & 0xFull;
  w[12] = m0 | (m1 << 4) | (m2 << 8) | (m3 << 12);
  u64 sel = 0;
#pragma unroll
  for (int i = 0; i < 13; ++i) sel = (lane == i) ? w[i] : sel;
  return sel;
}

// 256-elem row -> 4 packed u64 words; bit l of word j <-> element 64*j+l.
__device__ __forceinline__ u64 pack256_sel(const float* __restrict__ src, int lane) {
  u64 w[4];
#pragma unroll
  for (int j = 0; j < 4; ++j) w[j] = __ballot(src[j * 64 + lane] >= 0.0f);
  u64 sel = 0;
#pragma unroll
  for (int i = 0; i < 4; ++i) sel = (lane == i) ? w[i] : sel;
  return sel;
}

// Reduce the 16 stats replicas for (layer, col); gs = g*rsqrt(var+eps), mean_d.
__device__ __forceinline__ void bn_gs_md(const int* __restrict__ sumd_rep,
                                         const u64* __restrict__ sumdd_rep,
                                         int layer, int col,
                                         const float* __restrict__ g,
                                         float& gs, float& md_out) {
  long long sd = 0; u64 sdd = 0;
#pragma unroll
  for (int r = 0; r < NREP; ++r) {
    sd  += sumd_rep [(r * 5 + layer) * 256 + col];
    sdd += sumdd_rep[(r * 5 + layer) * 256 + col];
  }
  double md  = (double)sd  * (1.0 / 32768.0);
  double mdd = (double)sdd * (1.0 / 32768.0);
  float var = (float)(4.0 * (mdd - md * md));
  float s   = rsqrtf(var + 1e-5f);
  gs = g[col] * s;
  md_out = (float)md;
}

// ---------------- K1: pack all weights (transposed) + zero stats ----------------
__global__ __launch_bounds__(256) void pack_weights(
    const float* __restrict__ W0, const float* __restrict__ W1,
    const float* __restrict__ W2, const float* __restrict__ W3,
    const float* __restrict__ W4,
    u64* __restrict__ wb0, u64* __restrict__ wb1, u64* __restrict__ wb2,
    u64* __restrict__ wb3, u64* __restrict__ wb4, int4* __restrict__ statsZ) {
  const int b = blockIdx.x, tid = threadIdx.x;
  const int lane = tid & 63, wave = tid >> 6;
  int gid = b * 256 + tid;
  if (gid < STATS_INT4) statsZ[gid] = make_int4(0, 0, 0, 0);
  if (b < 64) {
    int row = b * 4 + wave;
    u64 sel = pack784_sel(W0 + (size_t)row * 784, 0.0f, lane);
    if (lane < 13) wb0[lane * 256 + row] = sel;
  } else if (b < 128) {
    int row = (b - 64) * 4 + wave;
    u64 sel = pack256_sel(W1 + (size_t)row * 256, lane);
    if (lane < 4) wb1[lane * 256 + row] = sel;
  } else if (b < 192) {
    int row = (b - 128) * 4 + wave;
    u64 sel = pack256_sel(W2 + (size_t)row * 256, lane);
    if (lane < 4) wb2[lane * 256 + row] = sel;
  } else if (b < 256) {
    int row = (b - 192) * 4 + wave;
    u64 sel = pack256_sel(W3 + (size_t)row * 256, lane);
    if (lane < 4) wb3[lane * 256 + row] = sel;
  } else {
    for (int row = wave; row < 10; row += 4) {
      u64 sel = pack256_sel(W4 + (size_t)row * 256, lane);
      if (lane < 4) wb4[lane * 16 + row] = sel;
    }
  }
}

// ---------------- K2: pack x tile -> LDS, layer-0 matmul, h0 + stats0 ----------------
__global__ __launch_bounds__(256, 8) void mm0_kernel(
    const float* __restrict__ x, const u64* __restrict__ wb0T,
    short* __restrict__ h0, int* __restrict__ sumd_rep, u64* __restrict__ sumdd_rep) {
  const int b = blockIdx.x, tid = threadIdx.x;
  const int lane = tid & 63, wave = tid >> 6;
  const int row0 = b * 16;
  __shared__ u64 a0T[16 * 16];
  // weight loads issued first (coalesced, independent of the pack phase)
  u64 w0r[13];
#pragma unroll
  for (int i = 0; i < 13; ++i) w0r[i] = wb0T[i * 256 + tid];
#pragma unroll
  for (int it = 0; it < 4; ++it) {
    int r = it * 4 + wave;
    u64 sel = pack784_sel(x + (size_t)(row0 + r) * 784, 0.5f, lane);
    if (lane < 16) a0T[r * 16 + lane] = sel;
  }
  __syncthreads();
  int sd = 0; unsigned sdd = 0;     // 16 * 784^2 = 9.8M, fits u32
#pragma unroll
  for (int r = 0; r < 16; ++r) {
    const ulonglong2* ap2 = (const ulonglong2*)&a0T[r * 16];
    int d = 0;
#pragma unroll
    for (int i = 0; i < 6; ++i) {
      ulonglong2 v = ap2[i];
      d += __popcll(v.x ^ w0r[2*i]) + __popcll(v.y ^ w0r[2*i+1]);
    }
    d += __popcll(a0T[r * 16 + 12] ^ w0r[12]);
    h0[(size_t)(row0 + r) * 256 + tid] = (short)(784 - 2 * d);
    sd += d; sdd += (unsigned)(d * d);
  }
  const int rep = b & (NREP - 1);
  atomicAdd(&sumd_rep [(rep * 5 + 0) * 256 + tid], sd);
  atomicAdd(&sumdd_rep[(rep * 5 + 0) * 256 + tid], (u64)sdd);
}

// ---------------- K3: binarize BN(h0) -> a1 bits, + layer-1 stats ----------------
__global__ __launch_bounds__(256, 8) void b0_kernel(
    const short* __restrict__ h0,
    int* __restrict__ sumd_rep, u64* __restrict__ sumdd_rep,
    const float* __restrict__ g0, const float* __restrict__ bb0,
    u64* __restrict__ a1, const u64* __restrict__ wb1T) {
  const int b = blockIdx.x, tid = threadIdx.x;
  const int lane = tid & 63, wave = tid >> 6;
  const int row0 = b * 32;
  float gs, md;
  bn_gs_md(sumd_rep, sumdd_rep, 0, tid, g0, gs, md);
  const float mh = 784.0f - 2.0f * md;
  const float bb = bb0[tid];
  __shared__ u64 bits[32 * 4];
#pragma unroll
  for (int r = 0; r < 32; ++r) {
    float hv = (float)h0[(size_t)(row0 + r) * 256 + tid];
    bool bit = fmaf(gs, hv - mh, bb) >= 0.0f;
    u64 m = __ballot(bit);
    if (lane == 0) bits[r * 4 + wave] = m;
  }
  __syncthreads();
  if (tid < 128) a1[(size_t)row0 * 4 + tid] = bits[tid];
  u64 wn[4];
#pragma unroll
  for (int i = 0; i < 4; ++i) wn[i] = wb1T[i * 256 + tid];   // coalesced
  int sd = 0; unsigned sdd = 0;     // 32 * 256^2 = 2.1M, fits u32
#pragma unroll
  for (int r = 0; r < 32; ++r) {
    int d = __popcll(bits[r*4+0] ^ wn[0]) + __popcll(bits[r*4+1] ^ wn[1])
          + __popcll(bits[r*4+2] ^ wn[2]) + __popcll(bits[r*4+3] ^ wn[3]);
    sd += d; sdd += (unsigned)(d * d);
  }
  const int rep = b & (NREP - 1);
  atomicAdd(&sumd_rep [(rep * 5 + 1) * 256 + tid], sd);
  atomicAdd(&sumdd_rep[(rep * 5 + 1) * 256 + tid], (u64)sdd);
}

// ---------------- K4..K6: layer k -> a_{k+1} bits + layer-(k+1) stats ----------------
// NSTRIDE: column stride of the transposed next-weight array (256 or 16).
template<int LAYER, int NNEXT, int NSTRIDE>
__global__ __launch_bounds__(256, 8) void bmid_kernel(
    const u64* __restrict__ aK, const u64* __restrict__ wbKT,
    int* __restrict__ sumd_rep, u64* __restrict__ sumdd_rep,
    const float* __restrict__ gK, const float* __restrict__ bK,
    u64* __restrict__ aN, const u64* __restrict__ wbNT) {
  const int b = blockIdx.x, tid = threadIdx.x;
  const int lane = tid & 63, wave = tid >> 6;
  const int row0 = b * 32;
  __shared__ u64 ain[32 * 4];
  __shared__ u64 bits[32 * 4];
  if (tid < 128) ain[tid] = aK[(size_t)row0 * 4 + tid];
  float gs, md;
  bn_gs_md(sumd_rep, sumdd_rep, LAYER, tid, gK, gs, md);
  const float A = -2.0f * gs;
  const float C = fmaf(gs, 2.0f * md, bK[tid]);
  u64 wk[4];
#pragma unroll
  for (int i = 0; i < 4; ++i) wk[i] = wbKT[i * 256 + tid];   // coalesced
  __syncthreads();
#pragma unroll
  for (int r = 0; r < 32; ++r) {
    int d = __popcll(ain[r*4+0] ^ wk[0]) + __popcll(ain[r*4+1] ^ wk[1])
          + __popcll(ain[r*4+2] ^ wk[2]) + __popcll(ain[r*4+3] ^ wk[3]);
    bool bit = fmaf(A, (float)d, C) >= 0.0f;
    u64 m = __ballot(bit);
    if (lane == 0) bits[r * 4 + wave] = m;
  }
  __syncthreads();
  if (tid < 128) aN[(size_t)row0 * 4 + tid] = bits[tid];
  if (tid < NNEXT) {
    u64 wn[4];
#pragma unroll
    for (int i = 0; i < 4; ++i) wn[i] = wbNT[i * NSTRIDE + tid];
    int sd = 0; unsigned sdd = 0;
#pragma unroll
    for (int r = 0; r < 32; ++r) {
      int d = __popcll(bits[r*4+0] ^ wn[0]) + __popcll(bits[r*4+1] ^ wn[1])
            + __popcll(bits[r*4+2] ^ wn[2]) + __popcll(bits[r*4+3] ^ wn[3]);
      sd += d; sdd += (unsigned)(d * d);
    }
    const int rep = b & (NREP - 1);
    atomicAdd(&sumd_rep [(rep * 5 + LAYER + 1) * 256 + tid], sd);
    atomicAdd(&sumdd_rep[(rep * 5 + LAYER + 1) * 256 + tid], (u64)sdd);
  }
}

// ---------------- K7: layer 4 + BN + softmax ----------------
__global__ __launch_bounds__(256) void b4_kernel(
    const u64* __restrict__ a4, const u64* __restrict__ wb4T,
    const int* __restrict__ sumd_rep, const u64* __restrict__ sumdd_rep,
    const float* __restrict__ g4, const float* __restrict__ bb4,
    float* __restrict__ out) {
  __shared__ float sA[10], sC[10];
  __shared__ u64 w4s[40];
  const int tid = threadIdx.x;
  if (tid < 40) w4s[tid] = wb4T[(tid & 3) * 16 + (tid >> 2)];   // w4s[c*4+i] = word i of class c
  if (tid < 10) {
    float gs, md;
    bn_gs_md(sumd_rep, sumdd_rep, 4, tid, g4, gs, md);
    sA[tid] = -2.0f * gs;
    sC[tid] = fmaf(gs, 2.0f * md, bb4[tid]);
  }
  __syncthreads();
  const int row = blockIdx.x * 256 + tid;
  u64 a[4];
#pragma unroll
  for (int i = 0; i < 4; ++i) a[i] = a4[(size_t)row * 4 + i];
  float y[10];
  float mx = -1e30f;
#pragma unroll
  for (int c = 0; c < 10; ++c) {
    int d = __popcll(a[0] ^ w4s[c*4+0]) + __popcll(a[1] ^ w4s[c*4+1])
          + __popcll(a[2] ^ w4s[c*4+2]) + __popcll(a[3] ^ w4s[c*4+3]);
    y[c] = fmaf(sA[c], (float)d, sC[c]);
    mx = fmaxf(mx, y[c]);
  }
  float sum = 0.0f;
#pragma unroll
  for (int c = 0; c < 10; ++c) { y[c] = __expf(y[c] - mx); sum += y[c]; }
  float inv = 1.0f / sum;
#pragma unroll
  for (int c = 0; c < 10; ++c) out[(size_t)row * 10 + c] = y[c] * inv;
}

// ---------------- host ----------------
extern "C" void kernel_launch(void* const* d_in, const int* in_sizes, int n_in,
                              void* d_out, int out_size, void* d_ws, size_t ws_size,
                              hipStream_t stream) {
  (void)in_sizes; (void)n_in; (void)out_size; (void)ws_size;
  const float* x   = (const float*)d_in[0];
  const float* W0  = (const float*)d_in[1];
  const float* g0  = (const float*)d_in[2];
  const float* bb0 = (const float*)d_in[3];
  const float* W1  = (const float*)d_in[4];
  const float* g1  = (const float*)d_in[5];
  const float* bb1 = (const float*)d_in[6];
  const float* W2  = (const float*)d_in[7];
  const float* g2  = (const float*)d_in[8];
  const float* bb2 = (const float*)d_in[9];
  const float* W3  = (const float*)d_in[10];
  const float* g3  = (const float*)d_in[11];
  const float* bb3 = (const float*)d_in[12];
  const float* W4  = (const float*)d_in[13];
  const float* g4  = (const float*)d_in[14];
  const float* bb4 = (const float*)d_in[15];

  char* ws = (char*)d_ws;
  u64*   wb0 = (u64*)(ws + OFF_WB0);
  u64*   wb1 = (u64*)(ws + OFF_WB1);
  u64*   wb2 = (u64*)(ws + OFF_WB2);
  u64*   wb3 = (u64*)(ws + OFF_WB3);
  u64*   wb4 = (u64*)(ws + OFF_WB4);
  int*   sumd  = (int*)(ws + OFF_SUMD);
  u64*   sumdd = (u64*)(ws + OFF_SUMDD);
  u64*   a1 = (u64*)(ws + OFF_A1);
  u64*   a2 = (u64*)(ws + OFF_A2);
  u64*   a3 = (u64*)(ws + OFF_A3);
  u64*   a4 = (u64*)(ws + OFF_A4);
  short* h0 = (short*)(ws + OFF_H0);

  pack_weights<<<257, 256, 0, stream>>>(W0, W1, W2, W3, W4,
                                        wb0, wb1, wb2, wb3, wb4,
                                        (int4*)(ws + OFF_SUMD));
  mm0_kernel<<<2048, 256, 0, stream>>>(x, wb0, h0, sumd, sumdd);
  b0_kernel<<<1024, 256, 0, stream>>>(h0, sumd, sumdd, g0, bb0, a1, wb1);
  bmid_kernel<1, 256, 256><<<1024, 256, 0, stream>>>(a1, wb1, sumd, sumdd, g1, bb1, a2, wb2);
  bmid_kernel<2, 256, 256><<<1024, 256, 0, stream>>>(a2, wb2, sumd, sumdd, g2, bb2, a3, wb3);
  bmid_kernel<3, 10, 16><<<1024, 256, 0, stream>>>(a3, wb3, sumd, sumdd, g3, bb3, a4, wb4);
  b4_kernel<<<128, 256, 0, stream>>>(a4, wb4, sumd, sumdd, g4, bb4, (float*)d_out);
}